// Round 1
// baseline (5710.313 us; speedup 1.0000x reference)
//
#include <hip/hip_runtime.h>
#include <hip/hip_bf16.h>
#include <math.h>

#define NN 50000
#define NE 800000
#define HD 128

// ---------------- degree computation ----------------
__global__ __launch_bounds__(256) void deg_kernel(const int* __restrict__ src,
                                                  const int* __restrict__ dst,
                                                  float* __restrict__ in_deg,
                                                  float* __restrict__ out_deg) {
    int e = blockIdx.x * 256 + threadIdx.x;
    if (e < NE) {
        atomicAdd(&in_deg[dst[e]], 1.0f);
        atomicAdd(&out_deg[src[e]], 1.0f);
    }
}

// ---------------- node init: norms + h0 ----------------
__global__ __launch_bounds__(256) void node_init_kernel(const float* __restrict__ cx,
                                                        const float* __restrict__ cy,
                                                        const float* __restrict__ in_deg,
                                                        const float* __restrict__ out_deg,
                                                        float* __restrict__ norm_s,
                                                        float* __restrict__ norm_d,
                                                        float* __restrict__ h0) {
    int i = blockIdx.x * 256 + threadIdx.x;
    if (i < NN) {
        float id = in_deg[i], od = out_deg[i];
        norm_s[i] = 1.0f / sqrtf(fmaxf(od, 1.0f));
        norm_d[i] = 1.0f / sqrtf(fmaxf(id, 1.0f));
        h0[i * 3 + 0] = id;
        h0[i * 3 + 1] = cx[i];
        h0[i * 3 + 2] = cy[i];
    }
}

// ---------------- layer-1 edge (F=3) ----------------
__global__ __launch_bounds__(256) void edge3_kernel(const int* __restrict__ src,
                                                    const int* __restrict__ dst,
                                                    const float* __restrict__ h0,
                                                    const float* __restrict__ norm_s,
                                                    float* __restrict__ agg3) {
    int e = blockIdx.x * 256 + threadIdx.x;
    if (e < NE) {
        int s = src[e], d = dst[e];
        float ns = norm_s[s];
        atomicAdd(&agg3[d * 3 + 0], h0[s * 3 + 0] * ns);
        atomicAdd(&agg3[d * 3 + 1], h0[s * 3 + 1] * ns);
        atomicAdd(&agg3[d * 3 + 2], h0[s * 3 + 2] * ns);
    }
}

// ---------------- layer-1 node (3 -> 128) ----------------
__global__ __launch_bounds__(256) void node3_kernel(const float* __restrict__ agg3,
                                                    const float* __restrict__ norm_d,
                                                    const float* __restrict__ W1,
                                                    const float* __restrict__ b1,
                                                    float* __restrict__ h1) {
    int gid = blockIdx.x * 256 + threadIdx.x;
    int i = gid >> 7, c = gid & 127;
    if (i < NN) {
        float nd = norm_d[i];
        float a0 = agg3[i * 3 + 0] * nd;
        float a1 = agg3[i * 3 + 1] * nd;
        float a2 = agg3[i * 3 + 2] * nd;
        float v = a0 * W1[c] + a1 * W1[128 + c] + a2 * W1[256 + c] + b1[c];
        h1[i * 128 + c] = fmaxf(v, 0.0f);
    }
}

// ---------------- edge aggregation, F=128 (atomic baseline) ----------------
// 32 threads per edge, each thread handles 4 consecutive features (float4 gather).
__global__ __launch_bounds__(256) void edge128_kernel(const int* __restrict__ src,
                                                      const int* __restrict__ dst,
                                                      const float* __restrict__ h,
                                                      const float* __restrict__ norm_s,
                                                      float* __restrict__ agg) {
    long gid = (long)blockIdx.x * 256 + threadIdx.x;
    int e = (int)(gid >> 5);
    int c4 = ((int)gid & 31) << 2;
    if (e < NE) {
        int s = src[e], d = dst[e];
        float ns = norm_s[s];
        const float4 v = *(const float4*)(h + (long)s * HD + c4);
        float* ap = agg + (long)d * HD + c4;
        atomicAdd(ap + 0, v.x * ns);
        atomicAdd(ap + 1, v.y * ns);
        atomicAdd(ap + 2, v.z * ns);
        atomicAdd(ap + 3, v.w * ns);
    }
}

// ---------------- node GEMM: out = relu((agg*norm_d) @ W + b) ----------------
// 64 rows per block, 256 threads. LDS tile [64][129] fp32 (pad kills bank conflicts).
// Thread t: rows (t>>5)*8 .. +7, cols (t&31)*4 .. +3 -> 8x4 register tile.
__global__ __launch_bounds__(256) void gemm_node_kernel(const float* __restrict__ agg,
                                                        const float* __restrict__ norm_d,
                                                        const float* __restrict__ W,
                                                        const float* __restrict__ b,
                                                        float* __restrict__ out) {
    __shared__ float lds[64][129];
    int row0 = blockIdx.x * 64;
    int t = threadIdx.x;

    // stage A tile (scaled by norm_d)
    #pragma unroll
    for (int i = 0; i < 8; ++i) {
        int idx = t + 256 * i;       // 0..2047
        int r = idx >> 5;            // 0..63
        int c4 = (idx & 31) << 2;    // 0..124
        int row = row0 + r;
        float4 v = make_float4(0.f, 0.f, 0.f, 0.f);
        float nd = 0.f;
        if (row < NN) {
            v = *(const float4*)(agg + (long)row * HD + c4);
            nd = norm_d[row];
        }
        lds[r][c4 + 0] = v.x * nd;
        lds[r][c4 + 1] = v.y * nd;
        lds[r][c4 + 2] = v.z * nd;
        lds[r][c4 + 3] = v.w * nd;
    }
    __syncthreads();

    int cg = (t & 31) << 2;   // col base
    int rg = (t >> 5) << 3;   // row base within tile

    float acc[8][4];
    #pragma unroll
    for (int i = 0; i < 8; ++i)
        #pragma unroll
        for (int j = 0; j < 4; ++j)
            acc[i][j] = 0.f;

    for (int k = 0; k < 128; ++k) {
        float4 w = *(const float4*)(W + (long)k * HD + cg);
        #pragma unroll
        for (int i = 0; i < 8; ++i) {
            float a = lds[rg + i][k];
            acc[i][0] += a * w.x;
            acc[i][1] += a * w.y;
            acc[i][2] += a * w.z;
            acc[i][3] += a * w.w;
        }
    }

    float b0 = b[cg + 0], b1 = b[cg + 1], b2 = b[cg + 2], b3 = b[cg + 3];
    for (int i = 0; i < 8; ++i) {
        int row = row0 + rg + i;
        if (row < NN) {
            float* op = out + (long)row * HD + cg;
            // scalar stores: layer-5 target (d_out+129 floats) is not 16B-aligned
            op[0] = fmaxf(acc[i][0] + b0, 0.f);
            op[1] = fmaxf(acc[i][1] + b1, 0.f);
            op[2] = fmaxf(acc[i][2] + b2, 0.f);
            op[3] = fmaxf(acc[i][3] + b3, 0.f);
        }
    }
}

// ---------------- column sum of h (for mean_nodes) ----------------
__global__ __launch_bounds__(256) void colsum_kernel(const float* __restrict__ h,
                                                     float* __restrict__ embsum) {
    int t = threadIdx.x;
    int c = t & 127;
    int rstart = blockIdx.x * 2 + (t >> 7);
    float acc = 0.f;
    for (int r = rstart; r < NN; r += gridDim.x * 2)
        acc += h[(long)r * HD + c];
    atomicAdd(&embsum[c], acc);
}

// ---------------- head MLP: emb -> relu(emb@Wl1+bl1) -> sigmoid(...) ----------------
__global__ __launch_bounds__(128) void head_kernel(const float* __restrict__ embsum,
                                                   const float* __restrict__ Wl1,
                                                   const float* __restrict__ bl1,
                                                   const float* __restrict__ Wl2,
                                                   const float* __restrict__ bl2,
                                                   float* __restrict__ d_out) {
    __shared__ float emb[128];
    __shared__ float hemb[64];
    int t = threadIdx.x;
    float e = embsum[t] * (1.0f / (float)NN);
    emb[t] = e;
    d_out[1 + t] = e;   // graph_emb
    __syncthreads();
    if (t < 64) {
        float acc = bl1[t];
        for (int k = 0; k < 128; ++k)
            acc += emb[k] * Wl1[k * 64 + t];
        hemb[t] = fmaxf(acc, 0.f);
    }
    __syncthreads();
    if (t == 0) {
        float acc = bl2[0];
        for (int j = 0; j < 64; ++j)
            acc += hemb[j] * Wl2[j];
        d_out[0] = 1.0f / (1.0f + expf(-acc));   // pred
    }
}

extern "C" void kernel_launch(void* const* d_in, const int* in_sizes, int n_in,
                              void* d_out, int out_size, void* d_ws, size_t ws_size,
                              hipStream_t stream) {
    const float* cx  = (const float*)d_in[0];
    const float* cy  = (const float*)d_in[1];
    const float* W1  = (const float*)d_in[2];
    const float* b1  = (const float*)d_in[3];
    const float* W2  = (const float*)d_in[4];
    const float* b2  = (const float*)d_in[5];
    const float* W3  = (const float*)d_in[6];
    const float* b3  = (const float*)d_in[7];
    const float* W4  = (const float*)d_in[8];
    const float* b4  = (const float*)d_in[9];
    const float* W5  = (const float*)d_in[10];
    const float* b5  = (const float*)d_in[11];
    const float* Wl1 = (const float*)d_in[12];
    const float* bl1 = (const float*)d_in[13];
    const float* Wl2 = (const float*)d_in[14];
    const float* bl2 = (const float*)d_in[15];
    const int*   src = (const int*)d_in[16];
    const int*   dst = (const int*)d_in[17];

    float* out = (float*)d_out;
    float* h_out = out + 129;          // final h lives directly in d_out

    // workspace layout (floats)
    float* ws      = (float*)d_ws;
    float* in_deg  = ws;                       // N
    float* out_deg = ws + NN;                  // N
    float* norm_s  = ws + 2 * NN;              // N
    float* norm_d  = ws + 3 * NN;              // N
    float* h0      = ws + 4 * NN;              // 3N
    float* agg3    = ws + 7 * NN;              // 3N
    float* hA      = ws + 10 * NN;             // 128N
    float* agg     = ws + 10 * NN + 128 * NN;  // 128N
    float* embsum  = ws + 10 * NN + 256 * NN;  // 128

    // 1. degrees
    hipMemsetAsync(in_deg, 0, 2 * NN * sizeof(float), stream);
    deg_kernel<<<(NE + 255) / 256, 256, 0, stream>>>(src, dst, in_deg, out_deg);

    // 2. norms + h0
    node_init_kernel<<<(NN + 255) / 256, 256, 0, stream>>>(cx, cy, in_deg, out_deg,
                                                           norm_s, norm_d, h0);

    // 3. layer 1 (F_in = 3)
    hipMemsetAsync(agg3, 0, 3 * NN * sizeof(float), stream);
    edge3_kernel<<<(NE + 255) / 256, 256, 0, stream>>>(src, dst, h0, norm_s, agg3);
    node3_kernel<<<(NN * 128) / 256, 256, 0, stream>>>(agg3, norm_d, W1, b1, hA);

    // 4. layers 2..5 (F_in = 128)
    const float* Ws[4] = {W2, W3, W4, W5};
    const float* bs[4] = {b2, b3, b4, b5};
    const int edge_blocks = (int)(((long)NE * 32 + 255) / 256);
    const int gemm_blocks = (NN + 63) / 64;
    for (int l = 0; l < 4; ++l) {
        hipMemsetAsync(agg, 0, (size_t)NN * HD * sizeof(float), stream);
        edge128_kernel<<<edge_blocks, 256, 0, stream>>>(src, dst, hA, norm_s, agg);
        float* dst_h = (l == 3) ? h_out : hA;
        gemm_node_kernel<<<gemm_blocks, 256, 0, stream>>>(agg, norm_d, Ws[l], bs[l], dst_h);
    }

    // 5. head
    hipMemsetAsync(embsum, 0, 128 * sizeof(float), stream);
    colsum_kernel<<<256, 256, 0, stream>>>(h_out, embsum);
    head_kernel<<<1, 128, 0, stream>>>(embsum, Wl1, bl1, Wl2, bl2, out);
}

// Round 2
// 765.576 us; speedup vs baseline: 7.4588x; 7.4588x over previous
//
#include <hip/hip_runtime.h>
#include <hip/hip_bf16.h>
#include <math.h>

#define NN 50000
#define NE 800000
#define HD 128

// ---------------- degree computation ----------------
__global__ __launch_bounds__(256) void deg_kernel(const int* __restrict__ src,
                                                  const int* __restrict__ dst,
                                                  float* __restrict__ in_deg,
                                                  float* __restrict__ out_deg) {
    int e = blockIdx.x * 256 + threadIdx.x;
    if (e < NE) {
        atomicAdd(&in_deg[dst[e]], 1.0f);
        atomicAdd(&out_deg[src[e]], 1.0f);
    }
}

// ---------------- node init: norms + h0 pre-scaled by norm_s ----------------
__global__ __launch_bounds__(256) void node_init_kernel(const float* __restrict__ cx,
                                                        const float* __restrict__ cy,
                                                        const float* __restrict__ in_deg,
                                                        const float* __restrict__ out_deg,
                                                        float* __restrict__ norm_s,
                                                        float* __restrict__ norm_d,
                                                        float* __restrict__ h0s) {
    int i = blockIdx.x * 256 + threadIdx.x;
    if (i < NN) {
        float id = in_deg[i], od = out_deg[i];
        float ns = 1.0f / sqrtf(fmaxf(od, 1.0f));
        norm_s[i] = ns;
        norm_d[i] = 1.0f / sqrtf(fmaxf(id, 1.0f));
        h0s[i * 3 + 0] = id * ns;
        h0s[i * 3 + 1] = cx[i] * ns;
        h0s[i * 3 + 2] = cy[i] * ns;
    }
}

// ---------------- CSR build: exclusive scan of in-degree counts ----------------
// single block, 256 threads, chunked Hillis-Steele scan over 50k entries
__global__ __launch_bounds__(256) void scan_kernel(const float* __restrict__ counts,
                                                   int* __restrict__ row_ptr) {
    __shared__ int buf[256];
    __shared__ int carry_s;
    int t = threadIdx.x;
    if (t == 0) carry_s = 0;
    __syncthreads();
    for (int base = 0; base < NN; base += 256) {
        int i = base + t;
        int v = (i < NN) ? (int)counts[i] : 0;
        buf[t] = v;
        __syncthreads();
        #pragma unroll
        for (int off = 1; off < 256; off <<= 1) {
            int add = (t >= off) ? buf[t - off] : 0;
            __syncthreads();
            buf[t] += add;
            __syncthreads();
        }
        int carry = carry_s;
        if (i < NN) row_ptr[i] = carry + buf[t] - v;   // exclusive
        __syncthreads();
        if (t == 255) carry_s = carry + buf[255];
        __syncthreads();
    }
    if (t == 0) row_ptr[NN] = carry_s;
}

// ---------------- CSR build: bucket scatter of src ids ----------------
__global__ __launch_bounds__(256) void fill_kernel(const int* __restrict__ src,
                                                   const int* __restrict__ dst,
                                                   const int* __restrict__ row_ptr,
                                                   int* __restrict__ cursor,
                                                   int* __restrict__ col) {
    int e = blockIdx.x * 256 + threadIdx.x;
    if (e < NE) {
        int d = dst[e];
        int pos = row_ptr[d] + atomicAdd(&cursor[d], 1);
        col[pos] = src[e];
    }
}

// ---------------- layer-1 gather (F=3), atomic-free ----------------
__global__ __launch_bounds__(256) void gather3_kernel(const int* __restrict__ row_ptr,
                                                      const int* __restrict__ col,
                                                      const float* __restrict__ h0s,
                                                      const float* __restrict__ norm_d,
                                                      float* __restrict__ agg3) {
    int n = blockIdx.x * 256 + threadIdx.x;
    if (n < NN) {
        float a0 = 0.f, a1 = 0.f, a2 = 0.f;
        int end = row_ptr[n + 1];
        for (int e = row_ptr[n]; e < end; ++e) {
            int s = col[e];
            a0 += h0s[s * 3 + 0];
            a1 += h0s[s * 3 + 1];
            a2 += h0s[s * 3 + 2];
        }
        float nd = norm_d[n];
        agg3[n * 3 + 0] = a0 * nd;
        agg3[n * 3 + 1] = a1 * nd;
        agg3[n * 3 + 2] = a2 * nd;
    }
}

// ---------------- layer-1 node (3 -> 128), output pre-scaled by norm_s ----------------
__global__ __launch_bounds__(256) void node3_kernel(const float* __restrict__ agg3,
                                                    const float* __restrict__ norm_s,
                                                    const float* __restrict__ W1,
                                                    const float* __restrict__ b1,
                                                    float* __restrict__ h1s) {
    int gid = blockIdx.x * 256 + threadIdx.x;
    int i = gid >> 7, c = gid & 127;
    if (i < NN) {
        float a0 = agg3[i * 3 + 0];
        float a1 = agg3[i * 3 + 1];
        float a2 = agg3[i * 3 + 2];
        float v = a0 * W1[c] + a1 * W1[128 + c] + a2 * W1[256 + c] + b1[c];
        h1s[i * 128 + c] = fmaxf(v, 0.0f) * norm_s[i];
    }
}

// ---------------- edge aggregation F=128: CSR gather, atomic-free ----------------
// 8 groups of 32 lanes per block; one node per group; lane owns 4 features.
__global__ __launch_bounds__(256) void gather128_kernel(const int* __restrict__ row_ptr,
                                                        const int* __restrict__ col,
                                                        const float* __restrict__ hs,
                                                        const float* __restrict__ norm_d,
                                                        float* __restrict__ agg) {
    int t = threadIdx.x;
    int g = t >> 5;
    int lane = t & 31;
    int n = blockIdx.x * 8 + g;
    if (n >= NN) return;
    int beg = row_ptr[n], end = row_ptr[n + 1];
    int c4 = lane << 2;
    float ax = 0.f, ay = 0.f, az = 0.f, aw = 0.f;
    int e = beg;
    for (; e + 1 < end; e += 2) {
        int s0 = col[e], s1 = col[e + 1];
        float4 v0 = *(const float4*)(hs + (long)s0 * HD + c4);
        float4 v1 = *(const float4*)(hs + (long)s1 * HD + c4);
        ax += v0.x + v1.x;
        ay += v0.y + v1.y;
        az += v0.z + v1.z;
        aw += v0.w + v1.w;
    }
    if (e < end) {
        int s0 = col[e];
        float4 v0 = *(const float4*)(hs + (long)s0 * HD + c4);
        ax += v0.x; ay += v0.y; az += v0.z; aw += v0.w;
    }
    float nd = norm_d[n];
    float4 o = make_float4(ax * nd, ay * nd, az * nd, aw * nd);
    *(float4*)(agg + (long)n * HD + c4) = o;
}

// ---------------- node GEMM: out = relu(agg @ W + b) [* scale] ----------------
// agg already carries norm_d; scale = norm_s for layers 1..4, nullptr for layer 5.
__global__ __launch_bounds__(256) void gemm_node_kernel(const float* __restrict__ agg,
                                                        const float* __restrict__ scale,
                                                        const float* __restrict__ W,
                                                        const float* __restrict__ b,
                                                        float* __restrict__ out) {
    __shared__ float lds[64][129];
    int row0 = blockIdx.x * 64;
    int t = threadIdx.x;

    #pragma unroll
    for (int i = 0; i < 8; ++i) {
        int idx = t + 256 * i;
        int r = idx >> 5;
        int c4 = (idx & 31) << 2;
        int row = row0 + r;
        float4 v = make_float4(0.f, 0.f, 0.f, 0.f);
        if (row < NN)
            v = *(const float4*)(agg + (long)row * HD + c4);
        lds[r][c4 + 0] = v.x;
        lds[r][c4 + 1] = v.y;
        lds[r][c4 + 2] = v.z;
        lds[r][c4 + 3] = v.w;
    }
    __syncthreads();

    int cg = (t & 31) << 2;
    int rg = (t >> 5) << 3;

    float acc[8][4];
    #pragma unroll
    for (int i = 0; i < 8; ++i)
        #pragma unroll
        for (int j = 0; j < 4; ++j)
            acc[i][j] = 0.f;

    for (int k = 0; k < 128; ++k) {
        float4 w = *(const float4*)(W + (long)k * HD + cg);
        #pragma unroll
        for (int i = 0; i < 8; ++i) {
            float a = lds[rg + i][k];
            acc[i][0] += a * w.x;
            acc[i][1] += a * w.y;
            acc[i][2] += a * w.z;
            acc[i][3] += a * w.w;
        }
    }

    float b0 = b[cg + 0], b1 = b[cg + 1], b2 = b[cg + 2], b3 = b[cg + 3];
    for (int i = 0; i < 8; ++i) {
        int row = row0 + rg + i;
        if (row < NN) {
            float sc = scale ? scale[row] : 1.0f;
            float* op = out + (long)row * HD + cg;
            op[0] = fmaxf(acc[i][0] + b0, 0.f) * sc;
            op[1] = fmaxf(acc[i][1] + b1, 0.f) * sc;
            op[2] = fmaxf(acc[i][2] + b2, 0.f) * sc;
            op[3] = fmaxf(acc[i][3] + b3, 0.f) * sc;
        }
    }
}

// ---------------- column sum of h (for mean_nodes) ----------------
__global__ __launch_bounds__(256) void colsum_kernel(const float* __restrict__ h,
                                                     float* __restrict__ embsum) {
    int t = threadIdx.x;
    int c = t & 127;
    int rstart = blockIdx.x * 2 + (t >> 7);
    float acc = 0.f;
    for (int r = rstart; r < NN; r += gridDim.x * 2)
        acc += h[(long)r * HD + c];
    atomicAdd(&embsum[c], acc);
}

// ---------------- head MLP ----------------
__global__ __launch_bounds__(128) void head_kernel(const float* __restrict__ embsum,
                                                   const float* __restrict__ Wl1,
                                                   const float* __restrict__ bl1,
                                                   const float* __restrict__ Wl2,
                                                   const float* __restrict__ bl2,
                                                   float* __restrict__ d_out) {
    __shared__ float emb[128];
    __shared__ float hemb[64];
    int t = threadIdx.x;
    float e = embsum[t] * (1.0f / (float)NN);
    emb[t] = e;
    d_out[1 + t] = e;
    __syncthreads();
    if (t < 64) {
        float acc = bl1[t];
        for (int k = 0; k < 128; ++k)
            acc += emb[k] * Wl1[k * 64 + t];
        hemb[t] = fmaxf(acc, 0.f);
    }
    __syncthreads();
    if (t == 0) {
        float acc = bl2[0];
        for (int j = 0; j < 64; ++j)
            acc += hemb[j] * Wl2[j];
        d_out[0] = 1.0f / (1.0f + expf(-acc));
    }
}

extern "C" void kernel_launch(void* const* d_in, const int* in_sizes, int n_in,
                              void* d_out, int out_size, void* d_ws, size_t ws_size,
                              hipStream_t stream) {
    const float* cx  = (const float*)d_in[0];
    const float* cy  = (const float*)d_in[1];
    const float* W1  = (const float*)d_in[2];
    const float* b1  = (const float*)d_in[3];
    const float* W2  = (const float*)d_in[4];
    const float* b2  = (const float*)d_in[5];
    const float* W3  = (const float*)d_in[6];
    const float* b3  = (const float*)d_in[7];
    const float* W4  = (const float*)d_in[8];
    const float* b4  = (const float*)d_in[9];
    const float* W5  = (const float*)d_in[10];
    const float* b5  = (const float*)d_in[11];
    const float* Wl1 = (const float*)d_in[12];
    const float* bl1 = (const float*)d_in[13];
    const float* Wl2 = (const float*)d_in[14];
    const float* bl2 = (const float*)d_in[15];
    const int*   src = (const int*)d_in[16];
    const int*   dst = (const int*)d_in[17];

    float* out = (float*)d_out;
    float* h_out = out + 129;             // final h lives in d_out

    // CSR lives in the d_out h-region: it is dead scratch until the layer-5
    // GEMM (which runs after the last gather) overwrites every element.
    int* row_ptr = (int*)h_out;           // N+1 ints
    int* col     = row_ptr + (NN + 1);    // E ints

    // workspace layout (floats)
    float* ws      = (float*)d_ws;
    float* norm_s  = ws;                   // N
    float* norm_d  = ws + NN;              // N
    float* in_deg  = ws + 2 * NN;          // N (counts; dead after scan)
    float* out_deg = ws + 3 * NN;          // N (dead after init -> cursor)
    int*   cursor  = (int*)out_deg;
    float* hs      = ws + 4 * NN;          // 128N
    float* agg     = ws + 132 * NN;        // 128N (h0s at +0, agg3 at +3N)
    float* h0s     = agg;                  // 3N
    float* agg3    = agg + 3 * NN;         // 3N
    float* embsum  = ws + 260 * NN;        // 128

    // 1. degrees
    hipMemsetAsync(in_deg, 0, 2 * NN * sizeof(float), stream);
    deg_kernel<<<(NE + 255) / 256, 256, 0, stream>>>(src, dst, in_deg, out_deg);

    // 2. norms + scaled h0
    node_init_kernel<<<(NN + 255) / 256, 256, 0, stream>>>(cx, cy, in_deg, out_deg,
                                                           norm_s, norm_d, h0s);

    // 3. CSR build
    scan_kernel<<<1, 256, 0, stream>>>(in_deg, row_ptr);
    hipMemsetAsync(cursor, 0, NN * sizeof(int), stream);
    fill_kernel<<<(NE + 255) / 256, 256, 0, stream>>>(src, dst, row_ptr, cursor, col);

    // 4. layer 1 (F_in = 3)
    gather3_kernel<<<(NN + 255) / 256, 256, 0, stream>>>(row_ptr, col, h0s, norm_d, agg3);
    node3_kernel<<<(NN * 128) / 256, 256, 0, stream>>>(agg3, norm_s, W1, b1, hs);

    // 5. layers 2..5 (F_in = 128), atomic-free CSR gather + node GEMM
    const float* Ws[4] = {W2, W3, W4, W5};
    const float* bs[4] = {b2, b3, b4, b5};
    const int gather_blocks = (NN + 7) / 8;
    const int gemm_blocks = (NN + 63) / 64;
    for (int l = 0; l < 4; ++l) {
        gather128_kernel<<<gather_blocks, 256, 0, stream>>>(row_ptr, col, hs, norm_d, agg);
        float* dst_h = (l == 3) ? h_out : hs;
        const float* sc = (l == 3) ? nullptr : norm_s;
        gemm_node_kernel<<<gemm_blocks, 256, 0, stream>>>(agg, sc, Ws[l], bs[l], dst_h);
    }

    // 6. head
    hipMemsetAsync(embsum, 0, 128 * sizeof(float), stream);
    colsum_kernel<<<256, 256, 0, stream>>>(h_out, embsum);
    head_kernel<<<1, 128, 0, stream>>>(embsum, Wl1, bl1, Wl2, bl2, out);
}

// Round 3
// 562.869 us; speedup vs baseline: 10.1450x; 1.3601x over previous
//
#include <hip/hip_runtime.h>
#include <hip/hip_bf16.h>
#include <math.h>

#define NN 50000
#define NE 800000
#define HD 128
#define SCAN_BLOCKS ((NN + 255) / 256)   // 196

// ---------------- degree computation ----------------
__global__ __launch_bounds__(256) void deg_kernel(const int* __restrict__ src,
                                                  const int* __restrict__ dst,
                                                  float* __restrict__ in_deg,
                                                  float* __restrict__ out_deg) {
    int e = blockIdx.x * 256 + threadIdx.x;
    if (e < NE) {
        atomicAdd(&in_deg[dst[e]], 1.0f);
        atomicAdd(&out_deg[src[e]], 1.0f);
    }
}

// ---------------- node init: norms + h0 pre-scaled by norm_s ----------------
__global__ __launch_bounds__(256) void node_init_kernel(const float* __restrict__ cx,
                                                        const float* __restrict__ cy,
                                                        const float* __restrict__ in_deg,
                                                        const float* __restrict__ out_deg,
                                                        float* __restrict__ norm_s,
                                                        float* __restrict__ norm_d,
                                                        float* __restrict__ h0s) {
    int i = blockIdx.x * 256 + threadIdx.x;
    if (i < NN) {
        float id = in_deg[i], od = out_deg[i];
        float ns = 1.0f / sqrtf(fmaxf(od, 1.0f));
        norm_s[i] = ns;
        norm_d[i] = 1.0f / sqrtf(fmaxf(id, 1.0f));
        h0s[i * 3 + 0] = id * ns;
        h0s[i * 3 + 1] = cx[i] * ns;
        h0s[i * 3 + 2] = cy[i] * ns;
    }
}

// ---------------- 3-pass parallel exclusive scan of in-degree counts ----------------
__global__ __launch_bounds__(256) void blocksum_kernel(const float* __restrict__ counts,
                                                       int* __restrict__ block_sums) {
    __shared__ int red[256];
    int t = threadIdx.x;
    int i = blockIdx.x * 256 + t;
    red[t] = (i < NN) ? (int)counts[i] : 0;
    __syncthreads();
    #pragma unroll
    for (int off = 128; off > 0; off >>= 1) {
        if (t < off) red[t] += red[t + off];
        __syncthreads();
    }
    if (t == 0) block_sums[blockIdx.x] = red[0];
}

__global__ __launch_bounds__(256) void scan_sums_kernel(int* __restrict__ block_sums) {
    __shared__ int buf[256];
    int t = threadIdx.x;
    int v = (t < SCAN_BLOCKS) ? block_sums[t] : 0;
    buf[t] = v;
    __syncthreads();
    #pragma unroll
    for (int off = 1; off < 256; off <<= 1) {
        int add = (t >= off) ? buf[t - off] : 0;
        __syncthreads();
        buf[t] += add;
        __syncthreads();
    }
    if (t < SCAN_BLOCKS) block_sums[t] = buf[t] - v;   // exclusive
}

__global__ __launch_bounds__(256) void rowptr_kernel(const float* __restrict__ counts,
                                                     const int* __restrict__ block_sums,
                                                     int* __restrict__ row_ptr) {
    __shared__ int buf[256];
    int t = threadIdx.x;
    int i = blockIdx.x * 256 + t;
    int v = (i < NN) ? (int)counts[i] : 0;
    buf[t] = v;
    __syncthreads();
    #pragma unroll
    for (int off = 1; off < 256; off <<= 1) {
        int add = (t >= off) ? buf[t - off] : 0;
        __syncthreads();
        buf[t] += add;
        __syncthreads();
    }
    if (i < NN) row_ptr[i] = block_sums[blockIdx.x] + buf[t] - v;
    if (i == 0) row_ptr[NN] = NE;   // total edge count is a constant
}

// ---------------- CSR build: bucket scatter of src ids ----------------
__global__ __launch_bounds__(256) void fill_kernel(const int* __restrict__ src,
                                                   const int* __restrict__ dst,
                                                   const int* __restrict__ row_ptr,
                                                   int* __restrict__ cursor,
                                                   int* __restrict__ col) {
    int e = blockIdx.x * 256 + threadIdx.x;
    if (e < NE) {
        int d = dst[e];
        int pos = row_ptr[d] + atomicAdd(&cursor[d], 1);
        col[pos] = src[e];
    }
}

// ---------------- layer-1 gather (F=3), atomic-free ----------------
__global__ __launch_bounds__(256) void gather3_kernel(const int* __restrict__ row_ptr,
                                                      const int* __restrict__ col,
                                                      const float* __restrict__ h0s,
                                                      const float* __restrict__ norm_d,
                                                      float* __restrict__ agg3) {
    int n = blockIdx.x * 256 + threadIdx.x;
    if (n < NN) {
        float a0 = 0.f, a1 = 0.f, a2 = 0.f;
        int end = row_ptr[n + 1];
        for (int e = row_ptr[n]; e < end; ++e) {
            int s = col[e];
            a0 += h0s[s * 3 + 0];
            a1 += h0s[s * 3 + 1];
            a2 += h0s[s * 3 + 2];
        }
        float nd = norm_d[n];
        agg3[n * 3 + 0] = a0 * nd;
        agg3[n * 3 + 1] = a1 * nd;
        agg3[n * 3 + 2] = a2 * nd;
    }
}

// ---------------- layer-1 node (3 -> 128), output pre-scaled by norm_s ----------------
__global__ __launch_bounds__(256) void node3_kernel(const float* __restrict__ agg3,
                                                    const float* __restrict__ norm_s,
                                                    const float* __restrict__ W1,
                                                    const float* __restrict__ b1,
                                                    float* __restrict__ h1s) {
    int gid = blockIdx.x * 256 + threadIdx.x;
    int i = gid >> 7, c = gid & 127;
    if (i < NN) {
        float a0 = agg3[i * 3 + 0];
        float a1 = agg3[i * 3 + 1];
        float a2 = agg3[i * 3 + 2];
        float v = a0 * W1[c] + a1 * W1[128 + c] + a2 * W1[256 + c] + b1[c];
        h1s[i * 128 + c] = fmaxf(v, 0.0f) * norm_s[i];
    }
}

// ---------------- edge aggregation F=128: CSR gather, atomic-free ----------------
__global__ __launch_bounds__(256) void gather128_kernel(const int* __restrict__ row_ptr,
                                                        const int* __restrict__ col,
                                                        const float* __restrict__ hs,
                                                        const float* __restrict__ norm_d,
                                                        float* __restrict__ agg) {
    int t = threadIdx.x;
    int g = t >> 5;
    int lane = t & 31;
    int n = blockIdx.x * 8 + g;
    if (n >= NN) return;
    int beg = row_ptr[n], end = row_ptr[n + 1];
    int c4 = lane << 2;
    float ax = 0.f, ay = 0.f, az = 0.f, aw = 0.f;
    int e = beg;
    for (; e + 1 < end; e += 2) {
        int s0 = col[e], s1 = col[e + 1];
        float4 v0 = *(const float4*)(hs + (long)s0 * HD + c4);
        float4 v1 = *(const float4*)(hs + (long)s1 * HD + c4);
        ax += v0.x + v1.x;
        ay += v0.y + v1.y;
        az += v0.z + v1.z;
        aw += v0.w + v1.w;
    }
    if (e < end) {
        int s0 = col[e];
        float4 v0 = *(const float4*)(hs + (long)s0 * HD + c4);
        ax += v0.x; ay += v0.y; az += v0.z; aw += v0.w;
    }
    float nd = norm_d[n];
    float4 o = make_float4(ax * nd, ay * nd, az * nd, aw * nd);
    *(float4*)(agg + (long)n * HD + c4) = o;
}

// ---------------- node GEMM: out = relu(agg @ W + b) [* scale] ----------------
__global__ __launch_bounds__(256) void gemm_node_kernel(const float* __restrict__ agg,
                                                        const float* __restrict__ scale,
                                                        const float* __restrict__ W,
                                                        const float* __restrict__ b,
                                                        float* __restrict__ out) {
    __shared__ float lds[64][129];
    int row0 = blockIdx.x * 64;
    int t = threadIdx.x;

    #pragma unroll
    for (int i = 0; i < 8; ++i) {
        int idx = t + 256 * i;
        int r = idx >> 5;
        int c4 = (idx & 31) << 2;
        int row = row0 + r;
        float4 v = make_float4(0.f, 0.f, 0.f, 0.f);
        if (row < NN)
            v = *(const float4*)(agg + (long)row * HD + c4);
        lds[r][c4 + 0] = v.x;
        lds[r][c4 + 1] = v.y;
        lds[r][c4 + 2] = v.z;
        lds[r][c4 + 3] = v.w;
    }
    __syncthreads();

    int cg = (t & 31) << 2;
    int rg = (t >> 5) << 3;

    float acc[8][4];
    #pragma unroll
    for (int i = 0; i < 8; ++i)
        #pragma unroll
        for (int j = 0; j < 4; ++j)
            acc[i][j] = 0.f;

    for (int k = 0; k < 128; ++k) {
        float4 w = *(const float4*)(W + (long)k * HD + cg);
        #pragma unroll
        for (int i = 0; i < 8; ++i) {
            float a = lds[rg + i][k];
            acc[i][0] += a * w.x;
            acc[i][1] += a * w.y;
            acc[i][2] += a * w.z;
            acc[i][3] += a * w.w;
        }
    }

    float b0 = b[cg + 0], b1 = b[cg + 1], b2 = b[cg + 2], b3 = b[cg + 3];
    for (int i = 0; i < 8; ++i) {
        int row = row0 + rg + i;
        if (row < NN) {
            float sc = scale ? scale[row] : 1.0f;
            float* op = out + (long)row * HD + cg;
            op[0] = fmaxf(acc[i][0] + b0, 0.f) * sc;
            op[1] = fmaxf(acc[i][1] + b1, 0.f) * sc;
            op[2] = fmaxf(acc[i][2] + b2, 0.f) * sc;
            op[3] = fmaxf(acc[i][3] + b3, 0.f) * sc;
        }
    }
}

// ---------------- column sum of h (for mean_nodes) ----------------
__global__ __launch_bounds__(256) void colsum_kernel(const float* __restrict__ h,
                                                     float* __restrict__ embsum) {
    int t = threadIdx.x;
    int c = t & 127;
    int rstart = blockIdx.x * 2 + (t >> 7);
    float acc = 0.f;
    for (int r = rstart; r < NN; r += gridDim.x * 2)
        acc += h[(long)r * HD + c];
    atomicAdd(&embsum[c], acc);
}

// ---------------- head MLP ----------------
__global__ __launch_bounds__(128) void head_kernel(const float* __restrict__ embsum,
                                                   const float* __restrict__ Wl1,
                                                   const float* __restrict__ bl1,
                                                   const float* __restrict__ Wl2,
                                                   const float* __restrict__ bl2,
                                                   float* __restrict__ d_out) {
    __shared__ float emb[128];
    __shared__ float hemb[64];
    int t = threadIdx.x;
    float e = embsum[t] * (1.0f / (float)NN);
    emb[t] = e;
    d_out[1 + t] = e;
    __syncthreads();
    if (t < 64) {
        float acc = bl1[t];
        for (int k = 0; k < 128; ++k)
            acc += emb[k] * Wl1[k * 64 + t];
        hemb[t] = fmaxf(acc, 0.f);
    }
    __syncthreads();
    if (t == 0) {
        float acc = bl2[0];
        for (int j = 0; j < 64; ++j)
            acc += hemb[j] * Wl2[j];
        d_out[0] = 1.0f / (1.0f + expf(-acc));
    }
}

extern "C" void kernel_launch(void* const* d_in, const int* in_sizes, int n_in,
                              void* d_out, int out_size, void* d_ws, size_t ws_size,
                              hipStream_t stream) {
    const float* cx  = (const float*)d_in[0];
    const float* cy  = (const float*)d_in[1];
    const float* W1  = (const float*)d_in[2];
    const float* b1  = (const float*)d_in[3];
    const float* W2  = (const float*)d_in[4];
    const float* b2  = (const float*)d_in[5];
    const float* W3  = (const float*)d_in[6];
    const float* b3  = (const float*)d_in[7];
    const float* W4  = (const float*)d_in[8];
    const float* b4  = (const float*)d_in[9];
    const float* W5  = (const float*)d_in[10];
    const float* b5  = (const float*)d_in[11];
    const float* Wl1 = (const float*)d_in[12];
    const float* bl1 = (const float*)d_in[13];
    const float* Wl2 = (const float*)d_in[14];
    const float* bl2 = (const float*)d_in[15];
    const int*   src = (const int*)d_in[16];
    const int*   dst = (const int*)d_in[17];

    float* out = (float*)d_out;
    float* h_out = out + 129;             // final h lives in d_out

    // CSR lives in the d_out h-region: dead scratch until layer-5 GEMM
    // (which runs after the last gather) overwrites every element.
    int* row_ptr = (int*)h_out;           // N+1 ints
    int* col     = row_ptr + (NN + 1);    // E ints

    // workspace layout (floats)
    float* ws      = (float*)d_ws;
    float* norm_s  = ws;                   // N
    float* norm_d  = ws + NN;              // N
    float* in_deg  = ws + 2 * NN;          // N (counts; dead after rowptr)
    float* out_deg = ws + 3 * NN;          // N (dead after init -> cursor)
    int*   cursor  = (int*)out_deg;
    float* hs      = ws + 4 * NN;          // 128N
    float* agg     = ws + 132 * NN;        // 128N (h0s at +0, agg3 at +3N)
    float* h0s     = agg;                  // 3N
    float* agg3    = agg + 3 * NN;         // 3N
    float* embsum  = ws + 260 * NN;        // 128
    int*   bsums   = (int*)(ws + 260 * NN + 128);   // SCAN_BLOCKS ints

    // 1. degrees
    hipMemsetAsync(in_deg, 0, 2 * NN * sizeof(float), stream);
    deg_kernel<<<(NE + 255) / 256, 256, 0, stream>>>(src, dst, in_deg, out_deg);

    // 2. norms + scaled h0
    node_init_kernel<<<(NN + 255) / 256, 256, 0, stream>>>(cx, cy, in_deg, out_deg,
                                                           norm_s, norm_d, h0s);

    // 3. CSR build (3-pass parallel scan + bucket scatter)
    blocksum_kernel<<<SCAN_BLOCKS, 256, 0, stream>>>(in_deg, bsums);
    scan_sums_kernel<<<1, 256, 0, stream>>>(bsums);
    rowptr_kernel<<<SCAN_BLOCKS, 256, 0, stream>>>(in_deg, bsums, row_ptr);
    hipMemsetAsync(cursor, 0, NN * sizeof(int), stream);
    fill_kernel<<<(NE + 255) / 256, 256, 0, stream>>>(src, dst, row_ptr, cursor, col);

    // 4. layer 1 (F_in = 3)
    gather3_kernel<<<(NN + 255) / 256, 256, 0, stream>>>(row_ptr, col, h0s, norm_d, agg3);
    node3_kernel<<<(NN * 128) / 256, 256, 0, stream>>>(agg3, norm_s, W1, b1, hs);

    // 5. layers 2..5 (F_in = 128), atomic-free CSR gather + node GEMM
    const float* Ws[4] = {W2, W3, W4, W5};
    const float* bs[4] = {b2, b3, b4, b5};
    const int gather_blocks = (NN + 7) / 8;
    const int gemm_blocks = (NN + 63) / 64;
    for (int l = 0; l < 4; ++l) {
        gather128_kernel<<<gather_blocks, 256, 0, stream>>>(row_ptr, col, hs, norm_d, agg);
        float* dst_h = (l == 3) ? h_out : hs;
        const float* sc = (l == 3) ? nullptr : norm_s;
        gemm_node_kernel<<<gemm_blocks, 256, 0, stream>>>(agg, sc, Ws[l], bs[l], dst_h);
    }

    // 6. head
    hipMemsetAsync(embsum, 0, 128 * sizeof(float), stream);
    colsum_kernel<<<256, 256, 0, stream>>>(h_out, embsum);
    head_kernel<<<1, 128, 0, stream>>>(embsum, Wl1, bl1, Wl2, bl2, out);
}